// Round 23
// baseline (95.794 us; speedup 1.0000x reference)
//
#include <hip/hip_runtime.h>

// Problem constants
#define SRC    16384     // 128*128 source pixels
#define DCH    64        // channels
#define NCLS   19        // classes
#define NPAIR  (NCLS*DCH)// 1216 (c,d) pairs

// Bare v_exp_f32 via inline asm (proven). Args always <= 0 here;
// flush-to-zero underflow matches reference f32 exp behavior.
__device__ __forceinline__ float exp2_raw(float x)
{
    float r;
    asm("v_exp_f32 %0, %1" : "=v"(r) : "v"(x));
    return r;
}

// Packed f32 ops (VOP3P, CDNA2+): one issue slot for two f32 lanes of math.
// R20 post-mortem: fused floor ~40us is VALU-ISSUE-bound (R15: measured
// VALU-busy 2.5x the naive model; occupancy/grid changes don't move it).
// Packing halves the non-trans issue slots.
typedef __attribute__((ext_vector_type(2))) float f32x2;

__device__ __forceinline__ f32x2 pk_fma(f32x2 a, f32x2 b, f32x2 c)
{
    f32x2 d;
    asm("v_pk_fma_f32 %0, %1, %2, %3" : "=v"(d) : "v"(a), "v"(b), "v"(c));
    return d;
}
__device__ __forceinline__ f32x2 pk_mul(f32x2 a, f32x2 b)
{
    f32x2 d;
    asm("v_pk_mul_f32 %0, %1, %2" : "=v"(d) : "v"(a), "v"(b));
    return d;
}
__device__ __forceinline__ f32x2 pk_add(f32x2 a, f32x2 b)
{
    f32x2 d;
    asm("v_pk_add_f32 %0, %1, %2" : "=v"(d) : "v"(a), "v"(b));
    return d;
}

// ---------------------------------------------------------------------------
// K1: per-source-pixel class counts (proven). Also zeroes psum.
// ---------------------------------------------------------------------------
__global__ __launch_bounds__(256) void hl_count_kernel(
    const int* __restrict__ label, unsigned char* __restrict__ cnt,
    float* __restrict__ psum)
{
    if (blockIdx.x == 0 && threadIdx.x == 0) psum[0] = 0.f;
    int s  = blockIdx.x * 256 + threadIdx.x;   // 64 blocks x 256 = 16384
    int sy = s >> 7, sx = s & 127;
    const int4* lab4 = (const int4*)label;
    int l[16];
#pragma unroll
    for (int r = 0; r < 4; r++) {
        int4 v = lab4[(4 * sy + r) * 128 + sx];
        l[4 * r + 0] = v.x; l[4 * r + 1] = v.y;
        l[4 * r + 2] = v.z; l[4 * r + 3] = v.w;
    }
#pragma unroll
    for (int c = 0; c < NCLS; c++) {
        int cc = 0;
#pragma unroll
        for (int j = 0; j < 16; j++) cc += (l[j] == c) ? 1 : 0;
        cnt[c * SRC + s] = (unsigned char)cc;
    }
}

// ---------------------------------------------------------------------------
// K2: fused moments + KDE. (256,8) occupancy budget (R20: fused 43.8 -> <40.7).
// Pass 1: UNCHANGED proven f64-reduced moments (bit-exact mu/istd).
// Pass 2: 7-exp k^2-CSE form, element-PAIRED with packed-f32 VALU:
//   per 2 elements: 19 pk ops (u,p,q,t1/t4/t9,6 args,7 accum) + 14 v_exp
//   vs 38 scalar VALU + 14 v_exp -- halves the non-trans issue slots that
//   R15/R20 showed to be the binding resource. Accumulators are f32x2;
//   .x+.y merged before the wave reduce (KDE-sum reorder only; moments
//   untouched). Scatter-free (R17 ledger: every scatter >= its savings).
// ---------------------------------------------------------------------------
__global__ __launch_bounds__(256, 8) void hl_fused_kernel(
    const float* __restrict__ feature, const unsigned char* __restrict__ cnt,
    int* __restrict__ ncls, float* __restrict__ psum)
{
    int w = blockIdx.x;             // pair 0..1215
    int c = w >> 6, d = w & 63;
    int t = threadIdx.x;
    int wid = t >> 6;

    const float4*       fp4 = (const float4*)(feature + d * SRC);
    const unsigned int* cpu = (const unsigned int*)(cnt + c * SRC);

    // ---- Pass 1: moments (proven, bit-exact, unchanged) -------------------
    float f1 = 0.f, f2 = 0.f;
    int   nc = 0;
#pragma unroll 4
    for (int i = 0; i < 16; i++) {
        int g = i * 256 + t;        // 4096 float4-groups (= 4096 uint groups)
        float4       x  = fp4[g];
        unsigned int cv = cpu[g];
        float xs[4] = {x.x, x.y, x.z, x.w};
        float cf[4] = {(float)(cv & 255u), (float)((cv >> 8) & 255u),
                       (float)((cv >> 16) & 255u), (float)(cv >> 24)};
#pragma unroll
        for (int e = 0; e < 4; e++) {
            float wx = cf[e] * xs[e];
            f1 += wx;
            f2 = fmaf(wx, xs[e], f2);
        }
        nc += (cv & 255u) + ((cv >> 8) & 255u) + ((cv >> 16) & 255u) + (cv >> 24);
    }
    double s1 = (double)f1, s2 = (double)f2;
#pragma unroll
    for (int o = 32; o > 0; o >>= 1) {
        s1 += __shfl_down(s1, o);
        s2 += __shfl_down(s2, o);
        nc += __shfl_down(nc, o);
    }
    __shared__ double ps1[4], ps2[4];
    __shared__ int    pn[4];
    __shared__ float  sh_mu, sh_istd;
    __shared__ int    sh_act;
    if ((t & 63) == 0) { ps1[wid] = s1; ps2[wid] = s2; pn[wid] = nc; }
    __syncthreads();
    if (t == 0) {
        double a = ps1[0] + ps1[1] + ps1[2] + ps1[3];
        double b = ps2[0] + ps2[1] + ps2[2] + ps2[3];
        int    n = pn[0] + pn[1] + pn[2] + pn[3];
        double nsafe = (n > 0) ? (double)n : 1.0;
        double mu  = a / nsafe;
        double var = (b - 2.0 * mu * a + mu * mu * (double)n) / nsafe + 1e-10;
        sh_mu   = (float)mu;
        sh_istd = (float)(1.0 / sqrt(var));
        sh_act  = (n >= 1000);
        if (d == 0) ncls[c] = n;    // plain store; consumed only by K3
    }
    __syncthreads();
    if (!sh_act) return;            // inactive class: contributes 0
    float istd = sh_istd;
    float nm   = -sh_mu * istd;     // u = fma(x, istd, nm)

    // ---- Pass 2: KDE, 7-exp k^2-CSE, packed-f32 element pairs -------------
    const float C1 = -18.033688011112042f;   // -12.5 * log2(e)
    const f32x2 C1v   = {C1, C1};
    const f32x2 C1x4  = {4.f * C1, 4.f * C1};
    const f32x2 C1x9  = {9.f * C1, 9.f * C1};
    const f32x2 K6    = { 6.f,  6.f};
    const f32x2 K4    = { 4.f,  4.f};
    const f32x2 K2    = { 2.f,  2.f};
    const f32x2 Kn2   = {-2.f, -2.f};
    const f32x2 Kn4   = {-4.f, -4.f};
    const f32x2 Kn6   = {-6.f, -6.f};
    const f32x2 istd2 = {istd, istd};
    const f32x2 nm2   = {nm, nm};

    f32x2 acc2[7];
#pragma unroll
    for (int j = 0; j < 7; j++) acc2[j] = (f32x2){0.f, 0.f};

#pragma unroll 2
    for (int i = 0; i < 16; i++) {
        int g = i * 256 + t;
        float4       x  = fp4[g];
        unsigned int cv = cpu[g];
        f32x2 xp[2]  = {{x.x, x.y}, {x.z, x.w}};
        f32x2 cfp[2] = {{(float)(cv & 255u),          (float)((cv >> 8) & 255u)},
                        {(float)((cv >> 16) & 255u),  (float)(cv >> 24)}};
#pragma unroll
        for (int h = 0; h < 2; h++) {
            f32x2 u  = pk_fma(xp[h], istd2, nm2);
            f32x2 p  = pk_mul(C1v, u);
            f32x2 q  = pk_mul(p, u);             // C1*u^2
            f32x2 t1 = pk_add(q, C1v);           // + C1*1
            f32x2 t4 = pk_add(q, C1x4);          // + C1*4
            f32x2 t9 = pk_add(q, C1x9);          // + C1*9
            f32x2 am3 = pk_fma(p, K6,  t9);      // k=-3
            f32x2 am2 = pk_fma(p, K4,  t4);      // k=-2
            f32x2 am1 = pk_fma(p, K2,  t1);      // k=-1
            f32x2 ap1 = pk_fma(p, Kn2, t1);      // k=+1
            f32x2 ap2 = pk_fma(p, Kn4, t4);      // k=+2
            f32x2 ap3 = pk_fma(p, Kn6, t9);      // k=+3
            f32x2 E;
            E.x = exp2_raw(am3.x); E.y = exp2_raw(am3.y);
            acc2[0] = pk_fma(cfp[h], E, acc2[0]);
            E.x = exp2_raw(am2.x); E.y = exp2_raw(am2.y);
            acc2[1] = pk_fma(cfp[h], E, acc2[1]);
            E.x = exp2_raw(am1.x); E.y = exp2_raw(am1.y);
            acc2[2] = pk_fma(cfp[h], E, acc2[2]);
            E.x = exp2_raw(q.x);   E.y = exp2_raw(q.y);
            acc2[3] = pk_fma(cfp[h], E, acc2[3]);
            E.x = exp2_raw(ap1.x); E.y = exp2_raw(ap1.y);
            acc2[4] = pk_fma(cfp[h], E, acc2[4]);
            E.x = exp2_raw(ap2.x); E.y = exp2_raw(ap2.y);
            acc2[5] = pk_fma(cfp[h], E, acc2[5]);
            E.x = exp2_raw(ap3.x); E.y = exp2_raw(ap3.y);
            acc2[6] = pk_fma(cfp[h], E, acc2[6]);
        }
    }

    __shared__ float part[4][7];
#pragma unroll
    for (int j = 0; j < 7; j++) {
        float v = acc2[j].x + acc2[j].y;
#pragma unroll
        for (int o = 32; o > 0; o >>= 1) v += __shfl_down(v, o);
        if ((t & 63) == 0) part[wid][j] = v;
    }
    __syncthreads();

    if (t == 0) {
        // target: exp(-0.5 k^2)/Z (1/sqrt(2 pi var) cancels in normalization)
        double e[7], z = 0.0;
#pragma unroll
        for (int k = -3; k <= 3; k++) { e[k + 3] = exp(-0.5 * (double)(k * k)); z += e[k + 3]; }

        float hist7[7], S = 0.f;
#pragma unroll
        for (int j = 0; j < 7; j++) {
            hist7[j] = part[0][j] + part[1][j] + part[2][j] + part[3][j];
            S += hist7[j];
        }
        float Ss = fmaxf(S, 1e-30f);
        float ps = 0.f;
#pragma unroll
        for (int j = 0; j < 7; j++) {
            float dd = fabsf(hist7[j] / Ss - (float)(e[j] / z));
            ps += (dd < 1.f) ? 0.5f * dd * dd : (dd - 0.5f);
        }
        atomicAdd(psum, ps);        // raw partial; scaled once in K3
    }
}

// ---------------------------------------------------------------------------
// K3: finalize. A = #active classes; out = psum / (448 * A). Writes out
// absolutely (harness-poisoned d_out needs no pre-zero).
// ---------------------------------------------------------------------------
__global__ __launch_bounds__(64) void hl_final_kernel(
    const float* __restrict__ psum, const int* __restrict__ ncls,
    float* __restrict__ out)
{
    if (threadIdx.x == 0) {
        int A = 0;
#pragma unroll
        for (int i = 0; i < NCLS; i++) A += (ncls[i] >= 1000) ? 1 : 0;
        out[0] = (A > 0) ? psum[0] / (448.0f * (float)A) : 0.0f;
    }
}

// ---------------------------------------------------------------------------
extern "C" void kernel_launch(void* const* d_in, const int* in_sizes, int n_in,
                              void* d_out, int out_size, void* d_ws, size_t ws_size,
                              hipStream_t stream)
{
    const float* feature = (const float*)d_in[0];   // [1,64,128,128] fp32
    const int*   label   = (const int*)d_in[1];     // [1,1,512,512]  int32
    float*       out     = (float*)d_out;           // scalar fp32

    char* ws = (char*)d_ws;
    unsigned char* cnt  = (unsigned char*)(ws);      // 311296 B
    int*           ncls = (int*)(ws + 311296);       // 76 B
    float*         psum = (float*)(ws + 311424);     // 4 B

    hl_count_kernel<<<SRC / 256, 256, 0, stream>>>(label, cnt, psum);
    hl_fused_kernel<<<NPAIR, 256, 0, stream>>>(feature, cnt, ncls, psum);
    hl_final_kernel<<<1, 64, 0, stream>>>(psum, ncls, out);
}